// Round 1
// baseline (2219.274 us; speedup 1.0000x reference)
//
#include <hip/hip_runtime.h>
#include <stdint.h>

#define B_  2048
#define T_  64
#define D_  512
#define S_  256
#define P_  11
#define H1_ 384
#define NG_ 1152   // H1 + 3S
#define KH_ 256

typedef unsigned short ushort_t;
typedef __attribute__((ext_vector_type(4))) float    f32x4;
typedef __attribute__((ext_vector_type(8))) __bf16   bf16x8;
typedef __attribute__((ext_vector_type(8))) unsigned short u16x8;

static __device__ __forceinline__ ushort_t f2bf(float f) {
    uint32_t u = __builtin_bit_cast(uint32_t, f);
    u += 0x7fffu + ((u >> 16) & 1u);
    return (ushort_t)(u >> 16);
}
static __device__ __forceinline__ float bf2f(ushort_t h) {
    uint32_t u = ((uint32_t)h) << 16;
    return __builtin_bit_cast(float, u);
}

// ---------------------------------------------------------------- pack weights
// WcatA [1152][512] bf16 : rows 0..383 = W1[:, :512]; rows 384..1151 = W_ih[:, :512]
// WhB   [1152][256] bf16 : rows 0..383 = W1[:, 512:768]; rows 384..1151 = W_hh
__global__ void pack_weights(const float* __restrict__ W1,   // [384][768]
                             const float* __restrict__ Wih,  // [768][513]
                             const float* __restrict__ Whh,  // [768][256]
                             ushort_t* __restrict__ WcatA,
                             ushort_t* __restrict__ WhB) {
    int idx = blockIdx.x * 256 + threadIdx.x;
    const int tot1 = NG_ * D_;                 // 589824
    if (idx < tot1) {
        int n = idx >> 9;
        int k = idx & 511;
        float v = (n < H1_) ? W1[n * 768 + k] : Wih[(n - H1_) * 513 + k];
        WcatA[idx] = f2bf(v);
    } else {
        int i = idx - tot1;                    // < 294912
        int n = i >> 8;
        int k = i & 255;
        float v = (n < H1_) ? W1[n * 768 + 512 + k] : Whh[(n - H1_) * 256 + k];
        WhB[n * 256 + k] = f2bf(v);
    }
}

// ---------------------------------------------------------------- phase A GEMM
// pre[t][b][n] = sum_k feat[(b,t)][k] * WcatA[n][k]   (bf16 out, fp32 accum)
__global__ __launch_bounds__(256) void gemm_pre(
        const float* __restrict__ feat,      // [131072][512], row m = b*64+t
        const ushort_t* __restrict__ WcatA,  // [1152][512]
        ushort_t* __restrict__ pre) {        // [64][2048][1152]
    __shared__ __attribute__((aligned(16))) ushort_t Asub[128][72];  // pad 64->72
    __shared__ __attribute__((aligned(16))) ushort_t Bsub[128][72];

    int bx = blockIdx.x;              // 9216 blocks
    int xcd = bx & 7, slot = bx >> 3; // co-locate N-siblings on one XCD
    int mt = (slot / 9) * 8 + xcd;    // 0..1023
    int ntb = slot % 9;               // 0..8
    int m0 = mt * 128, n0 = ntb * 128;

    int tid = threadIdx.x;
    int lane = tid & 63, wave = tid >> 6;
    int wr = wave >> 1, wc = wave & 1;
    int l15 = lane & 15, q = lane >> 4;

    f32x4 acc[4][4];
    #pragma unroll
    for (int i = 0; i < 4; ++i)
        #pragma unroll
        for (int j = 0; j < 4; ++j)
            acc[i][j] = (f32x4){0.f, 0.f, 0.f, 0.f};

    for (int kt = 0; kt < 8; ++kt) {
        int kbase = kt * 64;
        // stage A: fp32 -> bf16, 1024 chunks of 8 elems
        #pragma unroll
        for (int r = 0; r < 4; ++r) {
            int c = tid + 256 * r;
            int row = c >> 3, sub = c & 7;
            const float* gp = feat + (size_t)(m0 + row) * 512 + kbase + sub * 8;
            f32x4 f0 = *(const f32x4*)gp;
            f32x4 f1 = *(const f32x4*)(gp + 4);
            u16x8 o;
            #pragma unroll
            for (int j = 0; j < 4; ++j) { o[j] = f2bf(f0[j]); o[4 + j] = f2bf(f1[j]); }
            *(u16x8*)&Asub[row][sub * 8] = o;
        }
        // stage B: bf16 copy
        #pragma unroll
        for (int r = 0; r < 4; ++r) {
            int c = tid + 256 * r;
            int row = c >> 3, sub = c & 7;
            u16x8 w = *(const u16x8*)(WcatA + (size_t)(n0 + row) * 512 + kbase + sub * 8);
            *(u16x8*)&Bsub[row][sub * 8] = w;
        }
        __syncthreads();
        #pragma unroll
        for (int kc = 0; kc < 2; ++kc) {
            bf16x8 af[4], bfr[4];
            #pragma unroll
            for (int i = 0; i < 4; ++i)
                af[i] = __builtin_bit_cast(bf16x8,
                    *(const u16x8*)&Asub[wr * 64 + i * 16 + l15][kc * 32 + q * 8]);
            #pragma unroll
            for (int j = 0; j < 4; ++j)
                bfr[j] = __builtin_bit_cast(bf16x8,
                    *(const u16x8*)&Bsub[wc * 64 + j * 16 + l15][kc * 32 + q * 8]);
            #pragma unroll
            for (int i = 0; i < 4; ++i)
                #pragma unroll
                for (int j = 0; j < 4; ++j)
                    acc[i][j] = __builtin_amdgcn_mfma_f32_16x16x32_bf16(
                        af[i], bfr[j], acc[i][j], 0, 0, 0);
        }
        __syncthreads();
    }
    // epilogue: D[m][n], row=(q*4+reg), col=l15 per 16x16 tile; write to [t][b][n]
    #pragma unroll
    for (int i = 0; i < 4; ++i) {
        #pragma unroll
        for (int r = 0; r < 4; ++r) {
            int m = m0 + wr * 64 + i * 16 + q * 4 + r;
            int orow = (m & 63) * 2048 + (m >> 6);   // t*2048 + b
            ushort_t* op = pre + (size_t)orow * NG_ + n0 + wc * 64 + l15;
            #pragma unroll
            for (int j = 0; j < 4; ++j)
                op[j * 16] = f2bf(acc[i][j][r]);
        }
    }
}

// ---------------------------------------------------------------- phase B: recurrence
// 128 blocks x 512 threads; block owns 16 batch rows, loops t=0..63.
__global__ __launch_bounds__(512) void recurrent(
        const float* __restrict__ u,       // [2048][64][11]
        const float* __restrict__ b1,      // [384]
        const float* __restrict__ W2,      // [11][384]
        const float* __restrict__ b2,      // [11]
        const float* __restrict__ temp_p,  // [1]
        const float* __restrict__ Wih,     // [768][513] (col 512 = w_pos)
        const float* __restrict__ bih,     // [768]
        const float* __restrict__ bhh,     // [768]
        const float* __restrict__ h0,      // [256]
        const ushort_t* __restrict__ WhB,  // [1152][256] bf16
        const ushort_t* __restrict__ pre,  // [64][2048][1152] bf16
        float* __restrict__ out_pos,       // [2048][64]
        float* __restrict__ out_states,    // [2048][64][256]
        float* __restrict__ out_hfin) {    // [2048][256]
    __shared__ __attribute__((aligned(16))) float    gates[16][1156];  // stride: 2-way-bank-free, 16B rows
    __shared__ __attribute__((aligned(16))) ushort_t preg[16][768];    // pre, GRU part (n=384..1151)
    __shared__ __attribute__((aligned(16))) float    hf[16][256];      // h fp32
    __shared__ __attribute__((aligned(16))) ushort_t hb[16][264];      // h bf16 (padded)
    __shared__ __attribute__((aligned(16))) ushort_t hidb[16][392];    // hidden bf16 (padded)
    __shared__ __attribute__((aligned(16))) float    b1s[384];
    __shared__ __attribute__((aligned(16))) float    wps[768];
    __shared__ __attribute__((aligned(16))) float    bihs[768];
    __shared__ __attribute__((aligned(16))) float    bhhs[768];
    __shared__ float    b2s[16];
    __shared__ float    logit_s[16][17];
    __shared__ float    pos_s[16];
    __shared__ float    u_s[16][11];

    const int tid = threadIdx.x;
    const int lane = tid & 63, wave = tid >> 6;
    const int l15 = lane & 15, q = lane >> 4;
    const int b0 = blockIdx.x * 16;

    for (int i = tid; i < 384; i += 512) b1s[i] = b1[i];
    for (int i = tid; i < 768; i += 512) {
        wps[i]  = Wih[i * 513 + 512];
        bihs[i] = bih[i];
        bhhs[i] = bhh[i];
    }
    if (tid < 11) b2s[tid] = b2[tid];
    for (int i = tid; i < 16 * 256; i += 512) {
        int m = i >> 8, s = i & 255;
        float v = h0[s];
        hf[m][s] = v;
        hb[m][s] = f2bf(v);
    }
    float tinv = 1.0f / temp_p[0];

    bf16x8 w2f[12];   // W2 B-fragments, kept in regs (wave 0 uses)
    if (wave == 0) {
        #pragma unroll
        for (int kc = 0; kc < 12; ++kc) {
            u16x8 o = {0, 0, 0, 0, 0, 0, 0, 0};
            if (l15 < 11) {
                const float* gp = W2 + l15 * 384 + kc * 32 + q * 8;
                f32x4 f0 = *(const f32x4*)gp;
                f32x4 f1 = *(const f32x4*)(gp + 4);
                #pragma unroll
                for (int j = 0; j < 4; ++j) { o[j] = f2bf(f0[j]); o[4 + j] = f2bf(f1[j]); }
            }
            w2f[kc] = __builtin_bit_cast(bf16x8, o);
        }
    }
    __syncthreads();

    for (int t = 0; t < 64; ++t) {
        // A-fragments of h (written by previous step's GRU phase)
        bf16x8 af[8];
        #pragma unroll
        for (int kc = 0; kc < 8; ++kc)
            af[kc] = __builtin_bit_cast(bf16x8, *(const u16x8*)&hb[l15][kc * 32 + q * 8]);

        // prefetch this step's pre rows (GRU part -> LDS later; MLP part -> regs)
        const size_t prow = (size_t)(t * 2048 + b0);
        u16x8 pr[3];
        #pragma unroll
        for (int r = 0; r < 3; ++r) {
            int c = tid + 512 * r;              // < 1536 chunks (16 rows x 96)
            int row = c / 96, off = c % 96;
            pr[r] = *(const u16x8*)(pre + (prow + row) * NG_ + 384 + off * 8);
        }
        u16x8 p1[2];
        int p1m[2], p1sub[2];
        #pragma unroll
        for (int r = 0; r < 2; ++r) {
            int c = tid + 512 * r;              // < 768 chunks (16 rows x 48)
            p1m[r] = -1;
            if (c < 768) {
                int m = c / 48, sub = c - (c / 48) * 48;
                p1m[r] = m; p1sub[r] = sub;
                p1[r] = *(const u16x8*)(pre + (prow + m) * NG_ + sub * 8);
            }
        }
        float uval = 0.f;
        int um = tid / 11, up = tid - um * 11;
        if (tid < 176) uval = u[((size_t)(b0 + um) * 64 + t) * 11 + up];

        // gates GEMM: gates[16][1152] = h @ WhB^T  (wave w owns N-tiles w*9..w*9+8)
        const ushort_t* wbase = WhB + (size_t)(wave * 9 * 16 + l15) * 256 + q * 8;
        #pragma unroll
        for (int nt9 = 0; nt9 < 9; ++nt9) {
            f32x4 acc = (f32x4){0.f, 0.f, 0.f, 0.f};
            const ushort_t* wp = wbase + nt9 * 16 * 256;
            #pragma unroll
            for (int kc = 0; kc < 8; ++kc) {
                bf16x8 bfr = __builtin_bit_cast(bf16x8, *(const u16x8*)(wp + kc * 32));
                acc = __builtin_amdgcn_mfma_f32_16x16x32_bf16(af[kc], bfr, acc, 0, 0, 0);
            }
            int n = (wave * 9 + nt9) * 16 + l15;
            #pragma unroll
            for (int r = 0; r < 4; ++r)
                gates[q * 4 + r][n] = acc[r];
        }

        // commit staged pre/u to LDS
        #pragma unroll
        for (int r = 0; r < 3; ++r) {
            int c = tid + 512 * r;
            int row = c / 96, off = c % 96;
            *(u16x8*)&preg[row][off * 8] = pr[r];
        }
        if (tid < 176) u_s[um][up] = uval;
        __syncthreads();                                   // B1

        // hidden = relu(gates[:, :384] + pre1 + b1) -> bf16
        #pragma unroll
        for (int r = 0; r < 2; ++r) {
            if (p1m[r] >= 0) {
                int m = p1m[r], sub = p1sub[r];
                u16x8 o;
                #pragma unroll
                for (int j = 0; j < 8; ++j) {
                    float v = gates[m][sub * 8 + j] + bf2f(p1[r][j]) + b1s[sub * 8 + j];
                    o[j] = f2bf(fmaxf(v, 0.f));
                }
                *(u16x8*)&hidb[m][sub * 8] = o;
            }
        }
        __syncthreads();                                   // B2

        // logits = hidden @ W2^T (one 16x16 tile, K=384) — wave 0 only
        if (wave == 0) {
            f32x4 lacc = (f32x4){0.f, 0.f, 0.f, 0.f};
            #pragma unroll
            for (int kc = 0; kc < 12; ++kc) {
                bf16x8 ha = __builtin_bit_cast(bf16x8,
                    *(const u16x8*)&hidb[l15][kc * 32 + q * 8]);
                lacc = __builtin_amdgcn_mfma_f32_16x16x32_bf16(ha, w2f[kc], lacc, 0, 0, 0);
            }
            #pragma unroll
            for (int r = 0; r < 4; ++r)
                logit_s[q * 4 + r][l15] = lacc[r];
        }
        __syncthreads();                                   // B3

        // gumbel softmax + expected position (one thread per row)
        if (tid < 16) {
            int m = tid;
            float lg[11];
            float mx = -1e30f;
            #pragma unroll
            for (int p = 0; p < 11; ++p) {
                float uu = u_s[m][p];
                float g = -__logf(-__logf(uu + 1e-20f) + 1e-20f);
                float a = (logit_s[m][p] + b2s[p] + g) * tinv;
                lg[p] = a;
                mx = fmaxf(mx, a);
            }
            float se = 0.f, sp = 0.f;
            #pragma unroll
            for (int p = 0; p < 11; ++p) {
                float e = __expf(lg[p] - mx);
                se += e;
                sp += e * (float)p;
            }
            float pos = sp / se;
            pos_s[m] = pos;
            out_pos[(size_t)(b0 + m) * 64 + t] = pos;
        }
        __syncthreads();                                   // B4

        // GRU update: thread -> (m, 8 consecutive s)
        {
            int m = tid >> 5, s0 = (tid & 31) * 8;
            float pos = pos_s[m];
            u16x8 pir = *(const u16x8*)&preg[m][s0];
            u16x8 piz = *(const u16x8*)&preg[m][256 + s0];
            u16x8 pin = *(const u16x8*)&preg[m][512 + s0];
            float* st = out_states + ((size_t)(b0 + m) * 64 + t) * 256 + s0;
            #pragma unroll
            for (int j = 0; j < 8; ++j) {
                int s = s0 + j;
                float gr = gates[m][384 + s] + bhhs[s];
                float gz = gates[m][640 + s] + bhhs[256 + s];
                float gn = gates[m][896 + s] + bhhs[512 + s];
                float ir = bf2f(pir[j]) + pos * wps[s]       + bihs[s];
                float iz = bf2f(piz[j]) + pos * wps[256 + s] + bihs[256 + s];
                float in_ = bf2f(pin[j]) + pos * wps[512 + s] + bihs[512 + s];
                float rr = __builtin_amdgcn_rcpf(1.f + __expf(-(ir + gr)));
                float zz = __builtin_amdgcn_rcpf(1.f + __expf(-(iz + gz)));
                float nn = tanhf(in_ + rr * gn);
                float hnew = (1.f - zz) * nn + zz * hf[m][s];
                hf[m][s] = hnew;
                hb[m][s] = f2bf(hnew);
                st[j] = hnew;
            }
        }
        __syncthreads();                                   // B5
    }

    for (int i = tid; i < 16 * 256; i += 512) {
        int m = i >> 8, s = i & 255;
        out_hfin[(size_t)(b0 + m) * 256 + s] = hf[m][s];
    }
}

// ---------------------------------------------------------------- launch
extern "C" void kernel_launch(void* const* d_in, const int* in_sizes, int n_in,
                              void* d_out, int out_size, void* d_ws, size_t ws_size,
                              hipStream_t stream) {
    const float* feat = (const float*)d_in[0];
    const float* u    = (const float*)d_in[1];
    const float* W1   = (const float*)d_in[2];
    const float* b1   = (const float*)d_in[3];
    const float* W2   = (const float*)d_in[4];
    const float* b2   = (const float*)d_in[5];
    const float* temp = (const float*)d_in[6];
    const float* Wih  = (const float*)d_in[7];
    const float* bih  = (const float*)d_in[8];
    const float* Whh  = (const float*)d_in[9];
    const float* bhh  = (const float*)d_in[10];
    const float* h0   = (const float*)d_in[11];

    ushort_t* WcatA = (ushort_t*)d_ws;            // [1152][512]
    ushort_t* WhB   = WcatA + NG_ * D_;           // [1152][256]
    ushort_t* pre   = WhB + NG_ * KH_;            // [64][2048][1152]

    float* out_pos    = (float*)d_out;
    float* out_states = out_pos + (size_t)B_ * T_;
    float* out_hfin   = out_states + (size_t)B_ * T_ * S_;

    pack_weights<<<3456, 256, 0, stream>>>(W1, Wih, Whh, WcatA, WhB);
    gemm_pre<<<9216, 256, 0, stream>>>(feat, WcatA, pre);
    recurrent<<<128, 512, 0, stream>>>(u, b1, W2, b2, temp, Wih, bih, bhh, h0,
                                       WhB, pre, out_pos, out_states, out_hfin);
}

// Round 2
// 2097.553 us; speedup vs baseline: 1.0580x; 1.0580x over previous
//
#include <hip/hip_runtime.h>
#include <stdint.h>

#define B_  2048
#define T_  64
#define D_  512
#define S_  256
#define P_  11
#define H1_ 384
#define NG_ 1152   // H1 + 3S
#define KH_ 256

typedef unsigned short ushort_t;
typedef __attribute__((ext_vector_type(4))) float    f32x4;
typedef __attribute__((ext_vector_type(8))) __bf16   bf16x8;
typedef __attribute__((ext_vector_type(8))) unsigned short u16x8;

static __device__ __forceinline__ ushort_t f2bf(float f) {
    uint32_t u = __builtin_bit_cast(uint32_t, f);
    u += 0x7fffu + ((u >> 16) & 1u);
    return (ushort_t)(u >> 16);
}
static __device__ __forceinline__ float bf2f(ushort_t h) {
    uint32_t u = ((uint32_t)h) << 16;
    return __builtin_bit_cast(float, u);
}
static __device__ __forceinline__ u16x8 ntload8(const ushort_t* p) {
    return __builtin_nontemporal_load((const u16x8*)p);
}

// ---------------------------------------------------------------- pack weights
__global__ void pack_weights(const float* __restrict__ W1,   // [384][768]
                             const float* __restrict__ Wih,  // [768][513]
                             const float* __restrict__ Whh,  // [768][256]
                             ushort_t* __restrict__ WcatA,
                             ushort_t* __restrict__ WhB) {
    int idx = blockIdx.x * 256 + threadIdx.x;
    const int tot1 = NG_ * D_;                 // 589824
    if (idx < tot1) {
        int n = idx >> 9;
        int k = idx & 511;
        float v = (n < H1_) ? W1[n * 768 + k] : Wih[(n - H1_) * 513 + k];
        WcatA[idx] = f2bf(v);
    } else {
        int i = idx - tot1;                    // < 294912
        int n = i >> 8;
        int k = i & 255;
        float v = (n < H1_) ? W1[n * 768 + 512 + k] : Whh[(n - H1_) * 256 + k];
        WhB[n * 256 + k] = f2bf(v);
    }
}

// ---------------------------------------------------------------- phase A GEMM
// pre[t][b][n] = sum_k feat[(b,t)][k] * WcatA[n][k]   (bf16 out, fp32 accum)
__global__ __launch_bounds__(256) void gemm_pre(
        const float* __restrict__ feat,      // [131072][512], row m = b*64+t
        const ushort_t* __restrict__ WcatA,  // [1152][512]
        ushort_t* __restrict__ pre) {        // [64][2048][1152]
    __shared__ __attribute__((aligned(16))) ushort_t Asub[128][72];
    __shared__ __attribute__((aligned(16))) ushort_t Bsub[128][72];

    int bx = blockIdx.x;              // 9216 blocks
    int xcd = bx & 7, slot = bx >> 3;
    int mt = (slot / 9) * 8 + xcd;    // 0..1023
    int ntb = slot % 9;               // 0..8
    int m0 = mt * 128, n0 = ntb * 128;

    int tid = threadIdx.x;
    int lane = tid & 63, wave = tid >> 6;
    int wr = wave >> 1, wc = wave & 1;
    int l15 = lane & 15, q = lane >> 4;

    f32x4 acc[4][4];
    #pragma unroll
    for (int i = 0; i < 4; ++i)
        #pragma unroll
        for (int j = 0; j < 4; ++j)
            acc[i][j] = (f32x4){0.f, 0.f, 0.f, 0.f};

    for (int kt = 0; kt < 8; ++kt) {
        int kbase = kt * 64;
        #pragma unroll
        for (int r = 0; r < 4; ++r) {
            int c = tid + 256 * r;
            int row = c >> 3, sub = c & 7;
            const float* gp = feat + (size_t)(m0 + row) * 512 + kbase + sub * 8;
            f32x4 f0 = *(const f32x4*)gp;
            f32x4 f1 = *(const f32x4*)(gp + 4);
            u16x8 o;
            #pragma unroll
            for (int j = 0; j < 4; ++j) { o[j] = f2bf(f0[j]); o[4 + j] = f2bf(f1[j]); }
            *(u16x8*)&Asub[row][sub * 8] = o;
        }
        #pragma unroll
        for (int r = 0; r < 4; ++r) {
            int c = tid + 256 * r;
            int row = c >> 3, sub = c & 7;
            u16x8 w = *(const u16x8*)(WcatA + (size_t)(n0 + row) * 512 + kbase + sub * 8);
            *(u16x8*)&Bsub[row][sub * 8] = w;
        }
        __syncthreads();
        #pragma unroll
        for (int kc = 0; kc < 2; ++kc) {
            bf16x8 af[4], bfr[4];
            #pragma unroll
            for (int i = 0; i < 4; ++i)
                af[i] = __builtin_bit_cast(bf16x8,
                    *(const u16x8*)&Asub[wr * 64 + i * 16 + l15][kc * 32 + q * 8]);
            #pragma unroll
            for (int j = 0; j < 4; ++j)
                bfr[j] = __builtin_bit_cast(bf16x8,
                    *(const u16x8*)&Bsub[wc * 64 + j * 16 + l15][kc * 32 + q * 8]);
            #pragma unroll
            for (int i = 0; i < 4; ++i)
                #pragma unroll
                for (int j = 0; j < 4; ++j)
                    acc[i][j] = __builtin_amdgcn_mfma_f32_16x16x32_bf16(
                        af[i], bfr[j], acc[i][j], 0, 0, 0);
        }
        __syncthreads();
    }
    #pragma unroll
    for (int i = 0; i < 4; ++i) {
        #pragma unroll
        for (int r = 0; r < 4; ++r) {
            int m = m0 + wr * 64 + i * 16 + q * 4 + r;
            int orow = (m & 63) * 2048 + (m >> 6);   // t*2048 + b
            ushort_t* op = pre + (size_t)orow * NG_ + n0 + wc * 64 + l15;
            #pragma unroll
            for (int j = 0; j < 4; ++j)
                __builtin_nontemporal_store(f2bf(acc[i][j][r]), &op[j * 16]);
        }
    }
}

// ---------------------------------------------------------------- phase B: recurrence
// 128 blocks x 512 threads; block owns 16 batch rows, loops t=0..63.
__global__ __launch_bounds__(512) void recurrent(
        const float* __restrict__ u,       // [2048][64][11]
        const float* __restrict__ b1,      // [384]
        const float* __restrict__ W2,      // [11][384]
        const float* __restrict__ b2,      // [11]
        const float* __restrict__ temp_p,  // [1]
        const float* __restrict__ Wih,     // [768][513] (col 512 = w_pos)
        const float* __restrict__ bih,     // [768]
        const float* __restrict__ bhh,     // [768]
        const float* __restrict__ h0,      // [256]
        const ushort_t* __restrict__ WhB,  // [1152][256] bf16
        const ushort_t* __restrict__ pre,  // [64][2048][1152] bf16
        float* __restrict__ out_pos,       // [2048][64]
        float* __restrict__ out_states,    // [2048][64][256]
        float* __restrict__ out_hfin) {    // [2048][256]
    // all row strides chosen so stride % 32 dwords == 2 or 4 (no m-aliasing)
    __shared__ __attribute__((aligned(16))) ushort_t gates[16][1160];  // bf16 MFMA out
    __shared__ __attribute__((aligned(16))) ushort_t preg[16][1160];   // full pre row
    __shared__ __attribute__((aligned(16))) float    hf[16][256];      // h fp32
    __shared__ __attribute__((aligned(16))) ushort_t hb[16][264];      // h bf16
    __shared__ __attribute__((aligned(16))) ushort_t hidb[16][392];    // hidden bf16
    __shared__ __attribute__((aligned(16))) float    b1s[384];
    __shared__ __attribute__((aligned(16))) float    wps[768];
    __shared__ __attribute__((aligned(16))) float    bihs[768];
    __shared__ __attribute__((aligned(16))) float    bhhs[768];
    __shared__ float    b2s[16];
    __shared__ float    logit_s[16][17];
    __shared__ float    pos_s[16];
    __shared__ float    u_s[16][11];

    const int tid = threadIdx.x;
    const int lane = tid & 63, wave = tid >> 6;
    const int l15 = lane & 15, q = lane >> 4;
    const int b0 = blockIdx.x * 16;
    const int m_ew = tid >> 5;          // elementwise row (0..15)
    const int ln32 = tid & 31;          // elementwise lane (0..31)

    for (int i = tid; i < 384; i += 512) b1s[i] = b1[i];
    for (int i = tid; i < 768; i += 512) {
        wps[i]  = Wih[i * 513 + 512];
        bihs[i] = bih[i];
        bhhs[i] = bhh[i];
    }
    if (tid < 11) b2s[tid] = b2[tid];
    for (int i = tid; i < 16 * 256; i += 512) {
        int m = i >> 8, s = i & 255;
        float v = h0[s];
        hf[m][s] = v;
        hb[m][s] = f2bf(v);
    }
    float tinv = 1.0f / temp_p[0];

    bf16x8 w2f[12];   // W2 B-fragments (wave 0 uses)
    if (wave == 0) {
        #pragma unroll
        for (int kc = 0; kc < 12; ++kc) {
            u16x8 o = {0, 0, 0, 0, 0, 0, 0, 0};
            if (l15 < 11) {
                const float* gp = W2 + l15 * 384 + kc * 32 + q * 8;
                f32x4 f0 = *(const f32x4*)gp;
                f32x4 f1 = *(const f32x4*)(gp + 4);
                #pragma unroll
                for (int j = 0; j < 4; ++j) { o[j] = f2bf(f0[j]); o[4 + j] = f2bf(f1[j]); }
            }
            w2f[kc] = __builtin_bit_cast(bf16x8, o);
        }
    }
    __syncthreads();

    for (int t = 0; t < 64; ++t) {
        // A-fragments of h (written by previous step's GRU phase)
        bf16x8 af[8];
        #pragma unroll
        for (int kc = 0; kc < 8; ++kc)
            af[kc] = __builtin_bit_cast(bf16x8, *(const u16x8*)&hb[l15][kc * 32 + q * 8]);

        // prefetch this step's full pre rows (16 rows x 1152 = 2304 x u16x8)
        const size_t prow = (size_t)(t * 2048 + b0);
        u16x8 pr[5];
        #pragma unroll
        for (int r = 0; r < 5; ++r) {
            int c = tid + 512 * r;
            if (c < 2304) {
                int row = c / 144, off = c % 144;
                pr[r] = ntload8(pre + (prow + row) * NG_ + off * 8);
            }
        }
        float uval = 0.f;
        int um = tid / 11, up = tid - um * 11;
        if (tid < 176) uval = u[((size_t)(b0 + um) * 64 + t) * 11 + up];

        // gates GEMM: gates[16][1152] = h @ WhB^T (bf16 out)
        const ushort_t* wbase = WhB + (size_t)(wave * 9 * 16 + l15) * 256 + q * 8;
        #pragma unroll
        for (int nt9 = 0; nt9 < 9; ++nt9) {
            f32x4 acc = (f32x4){0.f, 0.f, 0.f, 0.f};
            const ushort_t* wp = wbase + nt9 * 16 * 256;
            #pragma unroll
            for (int kc = 0; kc < 8; ++kc) {
                bf16x8 bfr = __builtin_bit_cast(bf16x8, *(const u16x8*)(wp + kc * 32));
                acc = __builtin_amdgcn_mfma_f32_16x16x32_bf16(af[kc], bfr, acc, 0, 0, 0);
            }
            int n = (wave * 9 + nt9) * 16 + l15;
            #pragma unroll
            for (int r = 0; r < 4; ++r)
                gates[q * 4 + r][n] = f2bf(acc[r]);
        }

        // commit staged pre/u to LDS
        #pragma unroll
        for (int r = 0; r < 5; ++r) {
            int c = tid + 512 * r;
            if (c < 2304) {
                int row = c / 144, off = c % 144;
                *(u16x8*)&preg[row][off * 8] = pr[r];
            }
        }
        if (tid < 176) u_s[um][up] = uval;
        __syncthreads();                                   // B1

        // hidden = relu(gates[:, :384] + pre1 + b1) -> bf16  (lane-stride-1)
        #pragma unroll
        for (int j = 0; j < 12; ++j) {
            int c = ln32 + 32 * j;
            float v = bf2f(gates[m_ew][c]) + bf2f(preg[m_ew][c]) + b1s[c];
            hidb[m_ew][c] = f2bf(fmaxf(v, 0.f));
        }
        __syncthreads();                                   // B2

        // wave 0: logits MFMA + in-wave softmax (no extra barrier)
        if (wave == 0) {
            f32x4 lacc = (f32x4){0.f, 0.f, 0.f, 0.f};
            #pragma unroll
            for (int kc = 0; kc < 12; ++kc) {
                bf16x8 ha = __builtin_bit_cast(bf16x8,
                    *(const u16x8*)&hidb[l15][kc * 32 + q * 8]);
                lacc = __builtin_amdgcn_mfma_f32_16x16x32_bf16(ha, w2f[kc], lacc, 0, 0, 0);
            }
            #pragma unroll
            for (int r = 0; r < 4; ++r)
                logit_s[q * 4 + r][l15] = lacc[r];
            __builtin_amdgcn_s_waitcnt(0);   // drain LDS writes, then in-wave read
            if (lane < 16) {
                int m = lane;
                float lg[11];
                float mx = -1e30f;
                #pragma unroll
                for (int p = 0; p < 11; ++p) {
                    float uu = u_s[m][p];
                    float g = -__logf(-__logf(uu + 1e-20f) + 1e-20f);
                    float a = (logit_s[m][p] + b2s[p] + g) * tinv;
                    lg[p] = a;
                    mx = fmaxf(mx, a);
                }
                float se = 0.f, sp = 0.f;
                #pragma unroll
                for (int p = 0; p < 11; ++p) {
                    float e = __expf(lg[p] - mx);
                    se += e;
                    sp += e * (float)p;
                }
                float pos = sp / se;
                pos_s[m] = pos;
                __builtin_nontemporal_store(pos, &out_pos[(size_t)(b0 + m) * 64 + t]);
            }
        }

        // GRU partial sums (no pos dependency) — overlaps wave 0's softmax
        float a_r[8], a_z[8], i_n0[8], g_n[8], hprev[8];
        #pragma unroll
        for (int j = 0; j < 8; ++j) {
            int s = ln32 + 32 * j;
            a_r[j]  = bf2f(preg[m_ew][384 + s]) + bihs[s]
                    + bf2f(gates[m_ew][384 + s]) + bhhs[s];
            a_z[j]  = bf2f(preg[m_ew][640 + s]) + bihs[256 + s]
                    + bf2f(gates[m_ew][640 + s]) + bhhs[256 + s];
            i_n0[j] = bf2f(preg[m_ew][896 + s]) + bihs[512 + s];
            g_n[j]  = bf2f(gates[m_ew][896 + s]) + bhhs[512 + s];
            hprev[j] = hf[m_ew][s];
        }
        __syncthreads();                                   // B4 (pos visible)

        {
            float pos = pos_s[m_ew];
            float* st = out_states + ((size_t)(b0 + m_ew) * 64 + t) * 256;
            #pragma unroll
            for (int j = 0; j < 8; ++j) {
                int s = ln32 + 32 * j;
                float rr = __builtin_amdgcn_rcpf(1.f + __expf(-(a_r[j] + pos * wps[s])));
                float zz = __builtin_amdgcn_rcpf(1.f + __expf(-(a_z[j] + pos * wps[256 + s])));
                float xn = i_n0[j] + pos * wps[512 + s] + rr * g_n[j];
                float e2 = __expf(2.f * xn);
                float nn = 1.f - 2.f * __builtin_amdgcn_rcpf(e2 + 1.f);
                float hnew = (1.f - zz) * nn + zz * hprev[j];
                hf[m_ew][s] = hnew;
                hb[m_ew][s] = f2bf(hnew);
                __builtin_nontemporal_store(hnew, st + s);
            }
        }
        __syncthreads();                                   // B5
    }

    for (int i = tid; i < 16 * 256; i += 512) {
        int m = i >> 8, s = i & 255;
        __builtin_nontemporal_store(hf[m][s], &out_hfin[(size_t)(b0 + m) * 256 + s]);
    }
}

// ---------------------------------------------------------------- launch
extern "C" void kernel_launch(void* const* d_in, const int* in_sizes, int n_in,
                              void* d_out, int out_size, void* d_ws, size_t ws_size,
                              hipStream_t stream) {
    const float* feat = (const float*)d_in[0];
    const float* u    = (const float*)d_in[1];
    const float* W1   = (const float*)d_in[2];
    const float* b1   = (const float*)d_in[3];
    const float* W2   = (const float*)d_in[4];
    const float* b2   = (const float*)d_in[5];
    const float* temp = (const float*)d_in[6];
    const float* Wih  = (const float*)d_in[7];
    const float* bih  = (const float*)d_in[8];
    const float* Whh  = (const float*)d_in[9];
    const float* bhh  = (const float*)d_in[10];
    const float* h0   = (const float*)d_in[11];

    ushort_t* WcatA = (ushort_t*)d_ws;            // [1152][512]
    ushort_t* WhB   = WcatA + NG_ * D_;           // [1152][256]
    ushort_t* pre   = WhB + NG_ * KH_;            // [64][2048][1152]

    float* out_pos    = (float*)d_out;
    float* out_states = out_pos + (size_t)B_ * T_;
    float* out_hfin   = out_states + (size_t)B_ * T_ * S_;

    pack_weights<<<3456, 256, 0, stream>>>(W1, Wih, Whh, WcatA, WhB);
    gemm_pre<<<9216, 256, 0, stream>>>(feat, WcatA, pre);
    recurrent<<<128, 512, 0, stream>>>(u, b1, W2, b2, temp, Wih, bih, bhh, h0,
                                       WhB, pre, out_pos, out_states, out_hfin);
}